// Round 9
// baseline (207.653 us; speedup 1.0000x reference)
//
#include <hip/hip_runtime.h>
#include <math.h>

#define NEGV (-1e9f)
#define LOG2E 1.4426950408889634f

typedef _Float16 f16;
typedef __attribute__((ext_vector_type(2))) __fp16 hf2;
typedef __attribute__((ext_vector_type(4))) _Float16 f16x4;
typedef __attribute__((ext_vector_type(4))) float f32x4;

// ---------------------------------------------------------------------------
// prep: mbias[BN] (shared by all layers) + ones-rows (d=DH) of the 3 vT bufs
// ---------------------------------------------------------------------------
__global__ void prep_kernel(const int* __restrict__ mask, float* __restrict__ mbias,
                            f16* __restrict__ v1T, f16* __restrict__ v2T, f16* __restrict__ vvT,
                            int BN, int BHN, int N) {
    int t = blockIdx.x * blockDim.x + threadIdx.x;
    if (t < BN) { mbias[t] = mask[t] ? (-8.f * LOG2E) : NEGV; return; }
    t -= BN;
    if (t < BHN) { int bh = t / N, n = t % N; v1T[((size_t)bh * 16 + 12) * N + n] = (f16)1.f; return; }
    t -= BHN;
    if (t < BHN) { int bh = t / N, n = t % N; v2T[((size_t)bh * 16 + 4) * N + n] = (f16)1.f; return; }
    t -= BHN;
    if (t < BHN) { int bh = t / N, n = t % N; vvT[((size_t)bh * 16 + 4) * N + n] = (f16)1.f; }
}

// ---------------------------------------------------------------------------
// d1 feature-build + QKV -> f16 head-major Q (pre-scaled), K, transposed V.
// Q/K: [BH][N][12]; V^T: [BH][16][N] (row 12 = ones from prep; 13..15 unused)
// ---------------------------------------------------------------------------
__global__ void qkv1h_kernel(const float* __restrict__ r1, const float* __restrict__ r2,
                             const float* __restrict__ edge,
                             const float* __restrict__ wqkv, const float* __restrict__ bqkv,
                             f16* __restrict__ q1h, f16* __restrict__ k1h, f16* __restrict__ v1T,
                             int B, int M, int F, int H, float qmul) {
    const int N = M * M;
    const int BN = B * N;
    const int total = 3 * BN * 48;
    int t = blockIdx.x * blockDim.x + threadIdx.x;
    if (t >= total) return;
    int col = t % 48;
    int row = (t / 48) % BN;
    int mat = t / (48 * BN);
    int b = row / N, n = row % N;
    int i = n / M, j = n % M;

    const float* f1 = r1 + (b * M + i) * F;
    const float* f2 = r2 + (b * M + j) * F;
    const float* fe = edge + (size_t)row * F;
    const float* w  = wqkv + mat * 48 * 48 + col;

    float s = bqkv[mat * 48 + col];
#pragma unroll
    for (int d = 0; d < 16; ++d) s = fmaf(f1[d], w[d * 48], s);
#pragma unroll
    for (int d = 0; d < 16; ++d) s = fmaf(f2[d], w[(16 + d) * 48], s);
#pragma unroll
    for (int d = 0; d < 16; ++d) s = fmaf(fe[d], w[(32 + d) * 48], s);

    int h = col / 12, d = col % 12;
    int bh = b * H + h;
    if (mat == 0)      q1h[((size_t)bh * N + n) * 12 + d] = (f16)(s * qmul);
    else if (mat == 1) k1h[((size_t)bh * N + n) * 12 + d] = (f16)s;
    else               v1T[((size_t)bh * 16 + d) * N + n] = (f16)s;
}

// ---------------------------------------------------------------------------
// 16->16 QKV -> f16 head-major Q (pre-scaled), K, transposed V (DH=4).
// ---------------------------------------------------------------------------
__global__ void qkv16h_kernel(const float* __restrict__ in, const float* __restrict__ wqkv,
                              const float* __restrict__ bqkv,
                              f16* __restrict__ qh, f16* __restrict__ kh, f16* __restrict__ vT,
                              int BN, int N, int H, float qmul) {
    int t = blockIdx.x * blockDim.x + threadIdx.x;
    if (t >= 3 * BN * 16) return;
    int c = t % 16;
    int row = (t / 16) % BN;
    int mat = t / (16 * BN);
    const float* ir = in + (size_t)row * 16;
    const float* wc = wqkv + mat * 256 + c;
    float s = bqkv[mat * 16 + c];
#pragma unroll
    for (int d = 0; d < 16; ++d) s = fmaf(ir[d], wc[d * 16], s);

    int h = c / 4, d = c % 4;
    int b = row / N, n = row % N;
    int bh = b * H + h;
    if (mat == 0)      qh[((size_t)bh * N + n) * 4 + d] = (f16)(s * qmul);
    else if (mat == 1) kh[((size_t)bh * N + n) * 4 + d] = (f16)s;
    else               vT[((size_t)bh * 16 + d) * N + n] = (f16)s;
}

// ---------------------------------------------------------------------------
// Dual (pol + val) version.
// ---------------------------------------------------------------------------
__global__ void qkv16h_dual_kernel(const float* __restrict__ in,
                                   const float* __restrict__ wA, const float* __restrict__ bA,
                                   const float* __restrict__ wB, const float* __restrict__ bB,
                                   f16* __restrict__ qhA, f16* __restrict__ khA, f16* __restrict__ vTA,
                                   f16* __restrict__ qhB, f16* __restrict__ khB, f16* __restrict__ vTB,
                                   int BN, int N, int H, float qmul) {
    int t = blockIdx.x * blockDim.x + threadIdx.x;
    int tot = 3 * BN * 16;
    if (t >= 2 * tot) return;
    const float* w; const float* bb; f16* qh; f16* kh; f16* vT;
    int tt = t;
    if (t < tot) { w = wA; bb = bA; qh = qhA; kh = khA; vT = vTA; }
    else         { tt -= tot; w = wB; bb = bB; qh = qhB; kh = khB; vT = vTB; }
    int c = tt % 16;
    int row = (tt / 16) % BN;
    int mat = tt / (16 * BN);
    const float* ir = in + (size_t)row * 16;
    const float* wc = w + mat * 256 + c;
    float s = bb[mat * 16 + c];
#pragma unroll
    for (int d = 0; d < 16; ++d) s = fmaf(ir[d], wc[d * 16], s);

    int h = c / 4, d = c % 4;
    int b = row / N, n = row % N;
    int bh = b * H + h;
    if (mat == 0)      qh[((size_t)bh * N + n) * 4 + d] = (f16)(s * qmul);
    else if (mat == 1) kh[((size_t)bh * N + n) * 4 + d] = (f16)s;
    else               vT[((size_t)bh * 16 + d) * N + n] = (f16)s;
}

// ---------------------------------------------------------------------------
// Register-only MFMA flash attention partial (no LDS, no barriers):
//   S^T = mfma_16x16x16(A=K_frag, B=Q_frag, C=mbias)   (k = dh, Q zero-padded)
//   p = v_exp(S^T) in C/D layout == A-frag layout for PV mfma.
//   O/l = mfma(pa, vT_frag) with ones-row at d==DH (lanes d>DH discarded).
// All operands pre-converted f16 in global; inner loop = 3 loads + 2 MFMA +
// 4 raw v_exp pairs + 2 cvt_pkrtz. Block = 4 indep waves x QT*16 queries.
// grid: (BH or 2BH, N/(QT*64), N/256).
// ---------------------------------------------------------------------------
template <int DH, int QT>
__global__ __launch_bounds__(256, 8) void attn_reg_kernel(
    const f16* __restrict__ qh1, const f16* __restrict__ kh1, const f16* __restrict__ vT1,
    const f16* __restrict__ qh2, const f16* __restrict__ kh2, const f16* __restrict__ vT2,
    const float* __restrict__ mbias,
    float* __restrict__ pacc1, float* __restrict__ pl1,
    float* __restrict__ pacc2, float* __restrict__ pl2,
    int B, int H, int N) {
    const int LD = H * DH;
    const int BH = B * H;
    int bhs = blockIdx.x;
    const f16* qh; const f16* kh; const f16* vT; float* pacc; float* pl;
    if (bhs < BH) { qh = qh1; kh = kh1; vT = vT1; pacc = pacc1; pl = pl1; }
    else          { qh = qh2; kh = kh2; vT = vT2; pacc = pacc2; pl = pl2; bhs -= BH; }
    int b = bhs / H, h = bhs % H;
    int kbase = blockIdx.z * 256;
    int bN = b * N;

    int tid = threadIdx.x, lane = tid & 63, wid = tid >> 6;
    int lrow = lane & 15, lg = lane >> 4;
    int qbase = blockIdx.y * (QT * 64) + wid * (QT * 16);

    const f16* qB = qh + (size_t)bhs * N * DH;
    const f16* kB = kh + ((size_t)bhs * N + kbase) * DH + 4 * lg;
    const f16* vB = vT + ((size_t)bhs * 16 + lrow) * N + kbase + 4 * lg;
    const float* mB = mbias + bN + kbase + 4 * lg;

    f16x4 zf = {(f16)0.f, (f16)0.f, (f16)0.f, (f16)0.f};
    bool qok = (4 * lg < DH);
    f16x4 qf[QT];
#pragma unroll
    for (int qt = 0; qt < QT; ++qt)
        qf[qt] = qok ? *(const f16x4*)(qB + (size_t)(qbase + qt * 16 + lrow) * DH + 4 * lg) : zf;

    f32x4 oacc[QT];
#pragma unroll
    for (int qt = 0; qt < QT; ++qt) oacc[qt] = (f32x4){0.f, 0.f, 0.f, 0.f};

    for (int t16 = 0; t16 < 16; ++t16) {
        int k0 = t16 * 16;
        // K A-frag (row=key=lrow, k=dh; over-read past DH is zeroed by Q side)
        f16x4 kf = *(const f16x4*)(kB + (size_t)(k0 + lrow) * DH);
        // mask bias in C/D layout (row = key = 4lg+r)
        float4 mv = *(const float4*)(mB + k0);
        f32x4 mc = {mv.x, mv.y, mv.z, mv.w};
        // V^T B-frag (col=d=lrow, k=key=4lg+j); rows >DH garbage, never stored
        f16x4 vb = *(const f16x4*)(vB + k0);

#pragma unroll
        for (int qt = 0; qt < QT; ++qt) {
            f32x4 s = __builtin_amdgcn_mfma_f32_16x16x16f16(kf, qf[qt], mc, 0, 0, 0);
            hf2 lo = __builtin_amdgcn_cvt_pkrtz(__builtin_amdgcn_exp2f(s[0]),
                                                __builtin_amdgcn_exp2f(s[1]));
            hf2 hi = __builtin_amdgcn_cvt_pkrtz(__builtin_amdgcn_exp2f(s[2]),
                                                __builtin_amdgcn_exp2f(s[3]));
            f16x4 pa;
            ((hf2*)&pa)[0] = lo;
            ((hf2*)&pa)[1] = hi;
            oacc[qt] = __builtin_amdgcn_mfma_f32_16x16x16f16(pa, vb, oacc[qt], 0, 0, 0);
        }
    }

    // epilogue: C/D col = lrow = output dim (d<DH -> acc, d==DH -> l, else drop)
    int d = lrow;
    size_t zoff = (size_t)blockIdx.z * B * N;
#pragma unroll
    for (int qt = 0; qt < QT; ++qt) {
#pragma unroll
        for (int r = 0; r < 4; ++r) {
            int q = qbase + qt * 16 + lg * 4 + r;
            float val = oacc[qt][r];
            if (d < DH)
                pacc[(zoff + bN + q) * LD + h * DH + d] = val;
            else if (d == DH)
                pl[(zoff + bN + q) * H + h] = val;
        }
    }
}

// ---------------------------------------------------------------------------
// Sum partials over z and normalize: out[row][col] = sum_z acc / sum_z l
// ---------------------------------------------------------------------------
template <int DH>
__global__ void attn_combine_kernel(const float* __restrict__ pacc, const float* __restrict__ pl,
                                    float* __restrict__ out, int BN, int H, int ksplit) {
    const int LD = H * DH;
    int t = blockIdx.x * blockDim.x + threadIdx.x;
    if (t >= BN * LD) return;
    int row = t / LD, col = t % LD;
    int h = col / DH;
    float a = 0.f, lsum = 0.f;
    for (int z = 0; z < ksplit; ++z) {
        a    += pacc[((size_t)z * BN + row) * LD + col];
        lsum += pl[((size_t)z * BN + row) * H + h];
    }
    out[t] = a / lsum;
}

// ---------------------------------------------------------------------------
// out[row][col] = in[row][:KD] @ w[:,col] + b[col]; thread per output.
// ---------------------------------------------------------------------------
template <int KD>
__global__ void proj_kernel(const float* __restrict__ in, const float* __restrict__ w,
                            const float* __restrict__ bias, float* __restrict__ out,
                            int rows, int cols) {
    int t = blockIdx.x * blockDim.x + threadIdx.x;
    if (t >= rows * cols) return;
    int col = t % cols, row = t / cols;
    const float* ir = in + (size_t)row * KD;
    const float* wc = w + col;
    float s = bias[col];
#pragma unroll
    for (int d = 0; d < KD; ++d) s = fmaf(ir[d], wc[d * cols], s);
    out[t] = s;
}

// ---------------------------------------------------------------------------
// Fused d2 combine + proj16
// ---------------------------------------------------------------------------
__global__ void combine_proj16_kernel(const float* __restrict__ pacc, const float* __restrict__ pl,
                                      const float* __restrict__ w, const float* __restrict__ bias,
                                      float* __restrict__ out, int BN, int ksplit) {
    int t = blockIdx.x * blockDim.x + threadIdx.x;
    if (t >= BN * 16) return;
    int row = t / 16, col = t % 16;
    float ls0 = 0.f, ls1 = 0.f, ls2 = 0.f, ls3 = 0.f;
    for (int z = 0; z < ksplit; ++z) {
        const float* plr = pl + ((size_t)z * BN + row) * 4;
        ls0 += plr[0]; ls1 += plr[1]; ls2 += plr[2]; ls3 += plr[3];
    }
    float inv[4] = {1.f / ls0, 1.f / ls1, 1.f / ls2, 1.f / ls3};
    float s = bias[col];
#pragma unroll
    for (int d = 0; d < 16; ++d) {
        float a = 0.f;
        for (int z = 0; z < ksplit; ++z)
            a += pacc[((size_t)z * BN + row) * 16 + d];
        s = fmaf(a * inv[d >> 2], w[d * 16 + col], s);
    }
    out[t] = s;
}

// ---------------------------------------------------------------------------
// Fused pol/val combine + 16->1 head projections.
// ---------------------------------------------------------------------------
__global__ void heads_fused_kernel(const float* __restrict__ paccp, const float* __restrict__ plp,
                                   const float* __restrict__ paccv, const float* __restrict__ plv,
                                   const float* __restrict__ pol_wo, const float* __restrict__ pol_bo,
                                   const float* __restrict__ val_wo, const float* __restrict__ val_bo,
                                   float* __restrict__ act_raw, float* __restrict__ crit_raw,
                                   int BN, int ksplit) {
    int row = blockIdx.x * blockDim.x + threadIdx.x;
    if (row >= BN) return;

    float sa = pol_bo[0];
    {
        float ls[4] = {0.f, 0.f, 0.f, 0.f};
        for (int z = 0; z < ksplit; ++z) {
            const float* plr = plp + ((size_t)z * BN + row) * 4;
            ls[0] += plr[0]; ls[1] += plr[1]; ls[2] += plr[2]; ls[3] += plr[3];
        }
#pragma unroll
        for (int d = 0; d < 16; ++d) {
            float a = 0.f;
            for (int z = 0; z < ksplit; ++z)
                a += paccp[((size_t)z * BN + row) * 16 + d];
            sa = fmaf(a / ls[d >> 2], pol_wo[d], sa);
        }
    }
    float sc = val_bo[0];
    {
        float ls[4] = {0.f, 0.f, 0.f, 0.f};
        for (int z = 0; z < ksplit; ++z) {
            const float* plr = plv + ((size_t)z * BN + row) * 4;
            ls[0] += plr[0]; ls[1] += plr[1]; ls[2] += plr[2]; ls[3] += plr[3];
        }
#pragma unroll
        for (int d = 0; d < 16; ++d) {
            float a = 0.f;
            for (int z = 0; z < ksplit; ++z)
                a += paccv[((size_t)z * BN + row) * 16 + d];
            sc = fmaf(a / ls[d >> 2], val_wo[d], sc);
        }
    }
    act_raw[row] = sa;
    crit_raw[row] = sc;
}

// ---------------------------------------------------------------------------
// Final: blocks 0..B-1 masked action softmax; blocks B..2B-1 critic matvec.
// ---------------------------------------------------------------------------
__global__ __launch_bounds__(256) void final_kernel(
    const float* __restrict__ act_raw, const int* __restrict__ mask,
    const float* __restrict__ crit_raw, const float* __restrict__ v2w,
    const float* __restrict__ v2b,
    float* __restrict__ out_action, float* __restrict__ out_critic, int N, int B) {
    int tid = threadIdx.x;
    if ((int)blockIdx.x < B) {
        int b = blockIdx.x;
        int lane = tid & 63, wid = tid >> 6;
        __shared__ float wred[4];
        __shared__ float sbcast;

        float local[4];
        float mx = -INFINITY;
#pragma unroll
        for (int i = 0; i < 4; ++i) {
            int n = tid + i * 256;
            float a = act_raw[b * N + n];
            if (mask[b * N + n] == 0) a = NEGV;
            local[i] = a;
            mx = fmaxf(mx, a);
        }
#pragma unroll
        for (int o = 32; o > 0; o >>= 1) mx = fmaxf(mx, __shfl_down(mx, o));
        if (lane == 0) wred[wid] = mx;
        __syncthreads();
        if (tid == 0) sbcast = fmaxf(fmaxf(wred[0], wred[1]), fmaxf(wred[2], wred[3]));
        __syncthreads();
        mx = sbcast;

        float s = 0.f;
#pragma unroll
        for (int i = 0; i < 4; ++i) {
            float p = __expf(local[i] - mx);
            local[i] = p;
            s += p;
        }
#pragma unroll
        for (int o = 32; o > 0; o >>= 1) s += __shfl_down(s, o);
        if (lane == 0) wred[wid] = s;
        __syncthreads();
        if (tid == 0) sbcast = wred[0] + wred[1] + wred[2] + wred[3];
        __syncthreads();
        float inv = 1.f / sbcast;
#pragma unroll
        for (int i = 0; i < 4; ++i) out_action[b * N + tid + i * 256] = local[i] * inv;
    } else {
        int b = blockIdx.x - B;
        int c = tid & 15, seg = tid >> 4;
        __shared__ float red[16][17];
        float s = 0.f;
        int n0 = seg * 64;
        for (int n = n0; n < n0 + 64; ++n)
            s = fmaf(crit_raw[b * N + n], v2w[n * 16 + c], s);
        red[seg][c] = s;
        __syncthreads();
        if (tid < 16) {
            float acc = v2b[tid];
#pragma unroll
            for (int g = 0; g < 16; ++g) acc += red[g][tid];
            out_critic[b * 16 + tid] = acc;
        }
    }
}

// ---------------------------------------------------------------------------
extern "C" void kernel_launch(void* const* d_in, const int* in_sizes, int n_in,
                              void* d_out, int out_size, void* d_ws, size_t ws_size,
                              hipStream_t stream) {
    const int B = 16, M = 32, F = 16, H = 4;
    const int N = M * M;          // 1024
    const int BN = B * N;         // 16384
    const int BHN = B * H * N;    // 65536
    const int KSPLIT = 4;         // N / 256

    const float* r1       = (const float*)d_in[0];
    const float* r2       = (const float*)d_in[1];
    const float* edge     = (const float*)d_in[2];
    const int*   mask     = (const int*)d_in[3];
    const float* d1_wqkv  = (const float*)d_in[4];
    const float* d1_bqkv  = (const float*)d_in[5];
    const float* d1_wo    = (const float*)d_in[6];
    const float* d1_bo    = (const float*)d_in[7];
    const float* d2_wqkv  = (const float*)d_in[8];
    const float* d2_bqkv  = (const float*)d_in[9];
    const float* d2_wo    = (const float*)d_in[10];
    const float* d2_bo    = (const float*)d_in[11];
    const float* pol_wqkv = (const float*)d_in[12];
    const float* pol_bqkv = (const float*)d_in[13];
    const float* pol_wo   = (const float*)d_in[14];
    const float* pol_bo   = (const float*)d_in[15];
    const float* val_wqkv = (const float*)d_in[16];
    const float* val_bqkv = (const float*)d_in[17];
    const float* val_wo   = (const float*)d_in[18];
    const float* val_bo   = (const float*)d_in[19];
    const float* v2_w     = (const float*)d_in[20];
    const float* v2_b     = (const float*)d_in[21];

    // -------- workspace layout (floats) --------
    float* ws = (float*)d_ws;
    float* mbias = ws;                       // BN
    float* attn1 = mbias + BN;               // BN*48
    float* e1    = attn1 + BN * 48;          // BN*16
    float* e2    = e1 + BN * 16;             // BN*16
    float* araw  = e2 + BN * 16;             // BN
    float* craw  = araw + BN;                // BN
    float* pacc  = craw + BN;                // 4*BN*48 (d1; d2/pol use 4*BN*16 prefix)
    float* plp   = pacc + 4 * BN * 48;       // 4*BN*4
    float* plv   = plp + 4 * BN * 4;         // 4*BN*4
    // f16 region (K buffers never last: ~8B tail over-read is benign)
    f16* q1h = (f16*)(plv + 4 * BN * 4);     // BHN*12
    f16* k1h = q1h + (size_t)BHN * 12;       // BHN*12
    f16* q2h = k1h + (size_t)BHN * 12;       // BHN*4
    f16* k2h = q2h + (size_t)BHN * 4;        // BHN*4
    f16* qvh = k2h + (size_t)BHN * 4;        // BHN*4
    f16* kvh = qvh + (size_t)BHN * 4;        // BHN*4
    f16* v1T = kvh + (size_t)BHN * 4;        // BHN*16  ([BH][16][N])
    f16* v2T = v1T + (size_t)BHN * 16;       // BHN*16
    f16* vvT = v2T + (size_t)BHN * 16;       // BHN*16
    // pol overlays d2 operand buffers (dead after d2 attention)
    f16* qph = q2h; f16* kph = k2h; f16* vpT = v2T;
    // pol/val pacc split inside the big pacc buffer
    float* paccp = pacc;
    float* paccv = pacc + (size_t)KSPLIT * BN * 16;

    float* out_action = (float*)d_out;       // B*N
    float* out_critic = out_action + BN;     // B*16

    const float qmul1 = (1.0f / sqrtf(12.0f)) * LOG2E;
    const float qmul2 = 0.5f * LOG2E;

    // 1. prep: mbias + ones rows
    prep_kernel<<<(BN + 3 * BHN + 255) / 256, 256, 0, stream>>>(
        mask, mbias, v1T, v2T, vvT, BN, BHN, N);
    // 2. d1 feature-build + QKV (f16 head-major / transposed-V)
    qkv1h_kernel<<<(3 * BN * 48 + 255) / 256, 256, 0, stream>>>(
        r1, r2, edge, d1_wqkv, d1_bqkv, q1h, k1h, v1T, B, M, F, H, qmul1);
    // 3. d1 attention
    attn_reg_kernel<12, 2><<<dim3(B * H, N / 128, KSPLIT), 256, 0, stream>>>(
        q1h, k1h, v1T, q1h, k1h, v1T, mbias, pacc, plp, pacc, plp, B, H, N);
    // 4. combine
    attn_combine_kernel<12><<<(BN * 48 + 255) / 256, 256, 0, stream>>>(
        pacc, plp, attn1, BN, H, KSPLIT);
    // 5. e1 = attn1 @ d1_wo + d1_bo
    proj_kernel<48><<<(BN * 16 + 255) / 256, 256, 0, stream>>>(
        attn1, d1_wo, d1_bo, e1, BN, 16);
    // 6. d2 QKV
    qkv16h_kernel<<<(3 * BN * 16 + 255) / 256, 256, 0, stream>>>(
        e1, d2_wqkv, d2_bqkv, q2h, k2h, v2T, BN, N, H, qmul2);
    // 7. d2 attention
    attn_reg_kernel<4, 2><<<dim3(B * H, N / 128, KSPLIT), 256, 0, stream>>>(
        q2h, k2h, v2T, q2h, k2h, v2T, mbias, pacc, plp, pacc, plp, B, H, N);
    // 8. e2 = combine(d2) @ d2_wo + d2_bo
    combine_proj16_kernel<<<(BN * 16 + 255) / 256, 256, 0, stream>>>(
        pacc, plp, d2_wo, d2_bo, e2, BN, KSPLIT);
    // 9. pol + val QKV (pol overlays d2 buffers)
    qkv16h_dual_kernel<<<(2 * 3 * BN * 16 + 255) / 256, 256, 0, stream>>>(
        e2, pol_wqkv, pol_bqkv, val_wqkv, val_bqkv,
        qph, kph, vpT, qvh, kvh, vvT, BN, N, H, qmul2);
    // 10. pol + val attention (two sets in one launch)
    attn_reg_kernel<4, 2><<<dim3(2 * B * H, N / 128, KSPLIT), 256, 0, stream>>>(
        qph, kph, vpT, qvh, kvh, vvT, mbias, paccp, plp, paccv, plv, B, H, N);
    // 11. pol/val combine + head projections
    heads_fused_kernel<<<(BN + 255) / 256, 256, 0, stream>>>(
        paccp, plp, paccv, plv, pol_wo, pol_bo, val_wo, val_bo, araw, craw, BN, KSPLIT);
    // 12. masked action softmax + critic
    final_kernel<<<2 * B, 256, 0, stream>>>(
        araw, mask, craw, v2_w, v2_b, out_action, out_critic, N, B);
}

// Round 10
// 152.199 us; speedup vs baseline: 1.3644x; 1.3644x over previous
//
#include <hip/hip_runtime.h>
#include <math.h>

#define NEGV (-1e9f)
#define LOG2E 1.4426950408889634f

typedef _Float16 f16;
typedef __attribute__((ext_vector_type(2))) __fp16 hf2;
typedef __attribute__((ext_vector_type(4))) _Float16 f16x4;
typedef __attribute__((ext_vector_type(4))) float f32x4;

// ---------------------------------------------------------------------------
// K1: build f = [r1_bcast | r2_bcast | edge] on the fly and compute
//     qkv1[mat][row][col] = f_row @ d1_wqkv[mat] + d1_bqkv[mat]
// ---------------------------------------------------------------------------
__global__ void qkv1_kernel(const float* __restrict__ r1, const float* __restrict__ r2,
                            const float* __restrict__ edge,
                            const float* __restrict__ wqkv, const float* __restrict__ bqkv,
                            float* __restrict__ qkv1,
                            int B, int M, int F) {
    const int N = M * M;
    const int BN = B * N;
    const int total = 3 * BN * 48;
    int t = blockIdx.x * blockDim.x + threadIdx.x;
    if (t >= total) return;
    int col = t % 48;
    int row = (t / 48) % BN;
    int mat = t / (48 * BN);
    int b = row / N, n = row % N;
    int i = n / M, j = n % M;

    const float* f1 = r1 + (b * M + i) * F;
    const float* f2 = r2 + (b * M + j) * F;
    const float* fe = edge + (size_t)row * F;
    const float* w  = wqkv + mat * 48 * 48 + col;

    float s = bqkv[mat * 48 + col];
#pragma unroll
    for (int d = 0; d < 16; ++d) s = fmaf(f1[d], w[d * 48], s);
#pragma unroll
    for (int d = 0; d < 16; ++d) s = fmaf(f2[d], w[(16 + d) * 48], s);
#pragma unroll
    for (int d = 0; d < 16; ++d) s = fmaf(fe[d], w[(32 + d) * 48], s);
    qkv1[t] = s;
}

// ---------------------------------------------------------------------------
// Build a 16x16x16 MFMA fragment (4 f16, k = 4*lg + j) from a global f32 row,
// zero-padded past DH, scaled by mul.
// ---------------------------------------------------------------------------
template <int DH>
__device__ inline f16x4 load_frag4(const float* __restrict__ base, int lg, float mul) {
    f16x4 r;
    if (4 * lg < DH) {
        float4 v = *(const float4*)(base + 4 * lg);
        r[0] = (f16)(v.x * mul); r[1] = (f16)(v.y * mul);
        r[2] = (f16)(v.z * mul); r[3] = (f16)(v.w * mul);
    } else {
        r[0] = (f16)0.f; r[1] = (f16)0.f; r[2] = (f16)0.f; r[3] = (f16)0.f;
    }
    return r;
}

// ---------------------------------------------------------------------------
// LDS-staged MFMA flash attention partial:
//   K, V^T (f16, pre-converted once per block) and mask bias in LDS.
//   S^T = mfma_16x16x16(A=K_frag, B=Q_frag, C=mbias)  (k = dh, Q zero-padded:
//   K rows over-read past DH are nullified by the zero Q side)
//   p = raw v_exp2(S^T); C/D layout == A-frag layout for the PV mfma.
//   l folded via ones-row (d == DH) of V^T.
// No-max softmax in log2 domain with -8 shift folded into the C operand.
// Block = 4 waves x QT*16 queries, one (b,h), one 256-key chunk
// (blockIdx.z; gridDim.z MUST equal N/256). Two problem sets via blockIdx.x.
// ---------------------------------------------------------------------------
template <int DH, int QT>
__global__ __launch_bounds__(256, 8) void attn_lds_kernel(
    const float* __restrict__ q1, const float* __restrict__ k1, const float* __restrict__ v1,
    const float* __restrict__ q2, const float* __restrict__ k2, const float* __restrict__ v2,
    const int* __restrict__ mask,
    float* __restrict__ pacc1, float* __restrict__ pl1,
    float* __restrict__ pacc2, float* __restrict__ pl2,
    int B, int H, int N, float qmul) {
    const int LD = H * DH;
    const int BH = B * H;

    int bhs = blockIdx.x;
    const float* qg; const float* kg; const float* vg;
    float* pacc; float* pl;
    if (bhs < BH) { qg = q1; kg = k1; vg = v1; pacc = pacc1; pl = pl1; }
    else          { qg = q2; kg = k2; vg = v2; pacc = pacc2; pl = pl2; bhs -= BH; }
    int b = bhs / H, h = bhs % H;
    int kbase = blockIdx.z * 256;
    int bN = b * N;

    __shared__ __align__(16) f16 Kt[256][DH];   // K rows, f16 (over-read OK: Q zero-padded)
    __shared__ __align__(16) f16 Vt[16][264];   // V^T rows 0..DH-1, ones row DH, zero rest
    __shared__ __align__(16) float mbs[256];    // mask bias (log2 domain, incl -8 shift)

    int tid = threadIdx.x;
    // zero unused Vt rows DH+1..15
    for (int i = tid; i < (15 - DH) * 132; i += 256)
        ((int*)Vt)[(DH + 1) * 132 + i] = 0;
    {
        int kk = tid;  // 256 threads <-> 256 keys
        size_t g = ((size_t)(bN + kbase + kk)) * LD + h * DH;
        const float* krow = kg + g;
        const float* vrow = vg + g;
#pragma unroll
        for (int d = 0; d < DH; ++d) {
            Kt[kk][d] = (f16)krow[d];
            Vt[d][kk] = (f16)vrow[d];
        }
        Vt[DH][kk] = (f16)1.f;
        mbs[kk] = mask[bN + kbase + kk] ? (-8.f * LOG2E) : NEGV;
    }
    __syncthreads();

    int lane = tid & 63, wid = tid >> 6;
    int lrow = lane & 15, lg = lane >> 4;
    int qbase = blockIdx.y * (QT * 64) + wid * (QT * 16);

    // Q fragments (B-operand: col = query = lrow, k = dh), scale*log2e folded
    f16x4 qf[QT];
#pragma unroll
    for (int qt = 0; qt < QT; ++qt)
        qf[qt] = load_frag4<DH>(qg + ((size_t)(bN + qbase + qt * 16 + lrow)) * LD + h * DH, lg, qmul);

    f32x4 oacc[QT];
#pragma unroll
    for (int qt = 0; qt < QT; ++qt) oacc[qt] = (f32x4){0.f, 0.f, 0.f, 0.f};

#pragma unroll 4
    for (int t16 = 0; t16 < 16; ++t16) {
        // K A-frag from LDS (row = key = lrow, k = 4lg+j; cross-row read zeroed by Q)
        f16x4 kf = *(const f16x4*)(&Kt[0][0] + (size_t)(t16 * 16 + lrow) * DH + 4 * lg);
        // mask bias in C/D layout (row = key = 4lg+r)
        float4 mv = *(const float4*)(&mbs[t16 * 16 + 4 * lg]);
        f32x4 mc = {mv.x, mv.y, mv.z, mv.w};
        // V^T B-frag (col = d = lrow, k = key = 4lg+j)
        f16x4 vb = *(const f16x4*)(&Vt[lrow][t16 * 16 + 4 * lg]);

#pragma unroll
        for (int qt = 0; qt < QT; ++qt) {
            f32x4 s = __builtin_amdgcn_mfma_f32_16x16x16f16(kf, qf[qt], mc, 0, 0, 0);
            hf2 lo = __builtin_amdgcn_cvt_pkrtz(__builtin_amdgcn_exp2f(s[0]),
                                                __builtin_amdgcn_exp2f(s[1]));
            hf2 hi = __builtin_amdgcn_cvt_pkrtz(__builtin_amdgcn_exp2f(s[2]),
                                                __builtin_amdgcn_exp2f(s[3]));
            f16x4 pa;
            ((hf2*)&pa)[0] = lo;
            ((hf2*)&pa)[1] = hi;
            oacc[qt] = __builtin_amdgcn_mfma_f32_16x16x16f16(pa, vb, oacc[qt], 0, 0, 0);
        }
    }

    // epilogue: C/D col = lrow = output dim (d<DH -> acc, d==DH -> l, else drop)
    int d = lrow;
    size_t zoff = (size_t)blockIdx.z * B * N;
#pragma unroll
    for (int qt = 0; qt < QT; ++qt) {
#pragma unroll
        for (int r = 0; r < 4; ++r) {
            int q = qbase + qt * 16 + lg * 4 + r;
            float val = oacc[qt][r];
            if (d < DH)
                pacc[(zoff + bN + q) * LD + h * DH + d] = val;
            else if (d == DH)
                pl[(zoff + bN + q) * H + h] = val;
        }
    }
}

// ---------------------------------------------------------------------------
// Sum partials over z and normalize: out[row][col] = sum_z acc / sum_z l
// ---------------------------------------------------------------------------
template <int DH>
__global__ void attn_combine_kernel(const float* __restrict__ pacc, const float* __restrict__ pl,
                                    float* __restrict__ out, int BN, int H, int ksplit) {
    const int LD = H * DH;
    int t = blockIdx.x * blockDim.x + threadIdx.x;
    if (t >= BN * LD) return;
    int row = t / LD, col = t % LD;
    int h = col / DH;
    float a = 0.f, lsum = 0.f;
    for (int z = 0; z < ksplit; ++z) {
        a    += pacc[((size_t)z * BN + row) * LD + col];
        lsum += pl[((size_t)z * BN + row) * H + h];
    }
    out[t] = a / lsum;
}

// ---------------------------------------------------------------------------
// out[row][col] = in[row][:KD] @ w[:,col] + b[col]; thread per output.
// ---------------------------------------------------------------------------
template <int KD>
__global__ void proj_kernel(const float* __restrict__ in, const float* __restrict__ w,
                            const float* __restrict__ bias, float* __restrict__ out,
                            int rows, int cols) {
    int t = blockIdx.x * blockDim.x + threadIdx.x;
    if (t >= rows * cols) return;
    int col = t % cols, row = t / cols;
    const float* ir = in + (size_t)row * KD;
    const float* wc = w + col;
    float s = bias[col];
#pragma unroll
    for (int d = 0; d < KD; ++d) s = fmaf(ir[d], wc[d * cols], s);
    out[t] = s;
}

// ---------------------------------------------------------------------------
// qkv[mat][row][c] = in[row][:16] @ wqkv[mat][:,c] + bqkv[mat][c]
// ---------------------------------------------------------------------------
__global__ void qkv16_kernel(const float* __restrict__ in, const float* __restrict__ wqkv,
                             const float* __restrict__ bqkv, float* __restrict__ qkv,
                             int rows) {
    int t = blockIdx.x * blockDim.x + threadIdx.x;
    if (t >= 3 * rows * 16) return;
    int c = t % 16;
    int row = (t / 16) % rows;
    int mat = t / (16 * rows);
    const float* ir = in + (size_t)row * 16;
    const float* wc = wqkv + mat * 256 + c;
    float s = bqkv[mat * 16 + c];
#pragma unroll
    for (int d = 0; d < 16; ++d) s = fmaf(ir[d], wc[d * 16], s);
    qkv[t] = s;
}

// ---------------------------------------------------------------------------
// Two qkv16 problems (pol/val) in one launch.
// ---------------------------------------------------------------------------
__global__ void qkv16_dual_kernel(const float* __restrict__ in,
                                  const float* __restrict__ wA, const float* __restrict__ bA,
                                  const float* __restrict__ wB, const float* __restrict__ bB,
                                  float* __restrict__ qA, float* __restrict__ qB,
                                  int rows) {
    int t = blockIdx.x * blockDim.x + threadIdx.x;
    int tot = 3 * rows * 16;
    if (t >= 2 * tot) return;
    const float* w; const float* bb; float* q;
    int tt = t;
    if (t < tot) { w = wA; bb = bA; q = qA; }
    else         { tt -= tot; w = wB; bb = bB; q = qB; }
    int c = tt % 16;
    int row = (tt / 16) % rows;
    int mat = tt / (16 * rows);
    const float* ir = in + (size_t)row * 16;
    const float* wc = w + mat * 256 + c;
    float s = bb[mat * 16 + c];
#pragma unroll
    for (int d = 0; d < 16; ++d) s = fmaf(ir[d], wc[d * 16], s);
    q[tt] = s;
}

// ---------------------------------------------------------------------------
// Fused d2 combine + proj16: e2[row][col] = comb(row,:) @ w[:,col] + b[col]
// ---------------------------------------------------------------------------
__global__ void combine_proj16_kernel(const float* __restrict__ pacc, const float* __restrict__ pl,
                                      const float* __restrict__ w, const float* __restrict__ bias,
                                      float* __restrict__ out, int BN, int ksplit) {
    int t = blockIdx.x * blockDim.x + threadIdx.x;
    if (t >= BN * 16) return;
    int row = t / 16, col = t % 16;
    float ls0 = 0.f, ls1 = 0.f, ls2 = 0.f, ls3 = 0.f;
    for (int z = 0; z < ksplit; ++z) {
        const float* plr = pl + ((size_t)z * BN + row) * 4;
        ls0 += plr[0]; ls1 += plr[1]; ls2 += plr[2]; ls3 += plr[3];
    }
    float inv[4] = {1.f / ls0, 1.f / ls1, 1.f / ls2, 1.f / ls3};
    float s = bias[col];
#pragma unroll
    for (int d = 0; d < 16; ++d) {
        float a = 0.f;
        for (int z = 0; z < ksplit; ++z)
            a += pacc[((size_t)z * BN + row) * 16 + d];
        s = fmaf(a * inv[d >> 2], w[d * 16 + col], s);
    }
    out[t] = s;
}

// ---------------------------------------------------------------------------
// Fused pol/val combine + 16->1 head projections.
// ---------------------------------------------------------------------------
__global__ void heads_fused_kernel(const float* __restrict__ paccp, const float* __restrict__ plp,
                                   const float* __restrict__ paccv, const float* __restrict__ plv,
                                   const float* __restrict__ pol_wo, const float* __restrict__ pol_bo,
                                   const float* __restrict__ val_wo, const float* __restrict__ val_bo,
                                   float* __restrict__ act_raw, float* __restrict__ crit_raw,
                                   int BN, int ksplit) {
    int row = blockIdx.x * blockDim.x + threadIdx.x;
    if (row >= BN) return;

    float sa = pol_bo[0];
    {
        float ls[4] = {0.f, 0.f, 0.f, 0.f};
        for (int z = 0; z < ksplit; ++z) {
            const float* plr = plp + ((size_t)z * BN + row) * 4;
            ls[0] += plr[0]; ls[1] += plr[1]; ls[2] += plr[2]; ls[3] += plr[3];
        }
#pragma unroll
        for (int d = 0; d < 16; ++d) {
            float a = 0.f;
            for (int z = 0; z < ksplit; ++z)
                a += paccp[((size_t)z * BN + row) * 16 + d];
            sa = fmaf(a / ls[d >> 2], pol_wo[d], sa);
        }
    }
    float sc = val_bo[0];
    {
        float ls[4] = {0.f, 0.f, 0.f, 0.f};
        for (int z = 0; z < ksplit; ++z) {
            const float* plr = plv + ((size_t)z * BN + row) * 4;
            ls[0] += plr[0]; ls[1] += plr[1]; ls[2] += plr[2]; ls[3] += plr[3];
        }
#pragma unroll
        for (int d = 0; d < 16; ++d) {
            float a = 0.f;
            for (int z = 0; z < ksplit; ++z)
                a += paccv[((size_t)z * BN + row) * 16 + d];
            sc = fmaf(a / ls[d >> 2], val_wo[d], sc);
        }
    }
    act_raw[row] = sa;
    crit_raw[row] = sc;
}

// ---------------------------------------------------------------------------
// Final: blocks 0..B-1 masked action softmax; blocks B..2B-1 critic matvec.
// ---------------------------------------------------------------------------
__global__ __launch_bounds__(256) void final_kernel(
    const float* __restrict__ act_raw, const int* __restrict__ mask,
    const float* __restrict__ crit_raw, const float* __restrict__ v2w,
    const float* __restrict__ v2b,
    float* __restrict__ out_action, float* __restrict__ out_critic, int N, int B) {
    int tid = threadIdx.x;
    if ((int)blockIdx.x < B) {
        int b = blockIdx.x;
        int lane = tid & 63, wid = tid >> 6;
        __shared__ float wred[4];
        __shared__ float sbcast;

        float local[4];
        float mx = -INFINITY;
#pragma unroll
        for (int i = 0; i < 4; ++i) {
            int n = tid + i * 256;
            float a = act_raw[b * N + n];
            if (mask[b * N + n] == 0) a = NEGV;
            local[i] = a;
            mx = fmaxf(mx, a);
        }
#pragma unroll
        for (int o = 32; o > 0; o >>= 1) mx = fmaxf(mx, __shfl_down(mx, o));
        if (lane == 0) wred[wid] = mx;
        __syncthreads();
        if (tid == 0) sbcast = fmaxf(fmaxf(wred[0], wred[1]), fmaxf(wred[2], wred[3]));
        __syncthreads();
        mx = sbcast;

        float s = 0.f;
#pragma unroll
        for (int i = 0; i < 4; ++i) {
            float p = __expf(local[i] - mx);
            local[i] = p;
            s += p;
        }
#pragma unroll
        for (int o = 32; o > 0; o >>= 1) s += __shfl_down(s, o);
        if (lane == 0) wred[wid] = s;
        __syncthreads();
        if (tid == 0) sbcast = wred[0] + wred[1] + wred[2] + wred[3];
        __syncthreads();
        float inv = 1.f / sbcast;
#pragma unroll
        for (int i = 0; i < 4; ++i) out_action[b * N + tid + i * 256] = local[i] * inv;
    } else {
        int b = blockIdx.x - B;
        int c = tid & 15, seg = tid >> 4;
        __shared__ float red[16][17];
        float s = 0.f;
        int n0 = seg * 64;
        for (int n = n0; n < n0 + 64; ++n)
            s = fmaf(crit_raw[b * N + n], v2w[n * 16 + c], s);
        red[seg][c] = s;
        __syncthreads();
        if (tid < 16) {
            float acc = v2b[tid];
#pragma unroll
            for (int g = 0; g < 16; ++g) acc += red[g][tid];
            out_critic[b * 16 + tid] = acc;
        }
    }
}

// ---------------------------------------------------------------------------
extern "C" void kernel_launch(void* const* d_in, const int* in_sizes, int n_in,
                              void* d_out, int out_size, void* d_ws, size_t ws_size,
                              hipStream_t stream) {
    const int B = 16, M = 32, F = 16, H = 4;
    const int N = M * M;          // 1024
    const int BN = B * N;         // 16384
    const int KSPLIT = 4;         // MUST equal N/256 (kernel chunk = 256 keys)

    const float* r1       = (const float*)d_in[0];
    const float* r2       = (const float*)d_in[1];
    const float* edge     = (const float*)d_in[2];
    const int*   mask     = (const int*)d_in[3];
    const float* d1_wqkv  = (const float*)d_in[4];
    const float* d1_bqkv  = (const float*)d_in[5];
    const float* d1_wo    = (const float*)d_in[6];
    const float* d1_bo    = (const float*)d_in[7];
    const float* d2_wqkv  = (const float*)d_in[8];
    const float* d2_bqkv  = (const float*)d_in[9];
    const float* d2_wo    = (const float*)d_in[10];
    const float* d2_bo    = (const float*)d_in[11];
    const float* pol_wqkv = (const float*)d_in[12];
    const float* pol_bqkv = (const float*)d_in[13];
    const float* pol_wo   = (const float*)d_in[14];
    const float* pol_bo   = (const float*)d_in[15];
    const float* val_wqkv = (const float*)d_in[16];
    const float* val_bqkv = (const float*)d_in[17];
    const float* val_wo   = (const float*)d_in[18];
    const float* val_bo   = (const float*)d_in[19];
    const float* v2_w     = (const float*)d_in[20];
    const float* v2_b     = (const float*)d_in[21];

    float* ws = (float*)d_ws;
    float* qkv1     = ws;                           // 3*BN*48
    float* scr_pacc = qkv1 + 3 * BN * 48;           // 4*BN*48 (max)
    float* scr_pl   = scr_pacc + 4 * BN * 48;       // 8*BN*H
    float* attn1    = scr_pl + 8 * BN * H;          // BN*48
    float* e1       = attn1 + BN * 48;              // BN*16
    float* qkv2     = e1 + BN * 16;                 // 3*BN*16
    float* e2       = qkv2 + 3 * BN * 16;           // BN*16
    // overlays
    float* qkvp  = qkv1;                            // qkv1 dead after d1 attn
    float* qkvv  = qkv1 + 3 * BN * 16;
    float* araw  = e1;                              // e1 dead after qkv2
    float* craw  = e1 + BN;
    float* paccp = scr_pacc;
    float* paccv = scr_pacc + (size_t)KSPLIT * BN * 16;
    float* plp   = scr_pl;
    float* plv   = scr_pl + KSPLIT * BN * H;

    float* out_action = (float*)d_out;              // B*N
    float* out_critic = out_action + BN;            // B*16

    const float qmul1 = (1.0f / sqrtf(12.0f)) * LOG2E;
    const float qmul2 = 0.5f * LOG2E;

    // d1: feature build + QKV
    qkv1_kernel<<<(3 * BN * 48 + 255) / 256, 256, 0, stream>>>(
        r1, r2, edge, d1_wqkv, d1_bqkv, qkv1, B, M, F);
    // d1 attention (LDS-staged MFMA partial)
    attn_lds_kernel<12, 2><<<dim3(B * H, N / 128, KSPLIT), 256, 0, stream>>>(
        qkv1, qkv1 + BN * 48, qkv1 + 2 * BN * 48,
        qkv1, qkv1 + BN * 48, qkv1 + 2 * BN * 48,
        mask, scr_pacc, scr_pl, scr_pacc, scr_pl, B, H, N, qmul1);
    attn_combine_kernel<12><<<(BN * 48 + 255) / 256, 256, 0, stream>>>(
        scr_pacc, scr_pl, attn1, BN, H, KSPLIT);
    // e1 = attn1 @ d1_wo + d1_bo
    proj_kernel<48><<<(BN * 16 + 255) / 256, 256, 0, stream>>>(
        attn1, d1_wo, d1_bo, e1, BN, 16);
    // qkv2 = e1 @ d2_wqkv + d2_bqkv
    qkv16_kernel<<<(3 * BN * 16 + 255) / 256, 256, 0, stream>>>(
        e1, d2_wqkv, d2_bqkv, qkv2, BN);
    // d2 attention
    attn_lds_kernel<4, 2><<<dim3(B * H, N / 128, KSPLIT), 256, 0, stream>>>(
        qkv2, qkv2 + BN * 16, qkv2 + 2 * BN * 16,
        qkv2, qkv2 + BN * 16, qkv2 + 2 * BN * 16,
        mask, scr_pacc, scr_pl, scr_pacc, scr_pl, B, H, N, qmul2);
    // e2 = combine(d2) @ d2_wo + d2_bo  (fused)
    combine_proj16_kernel<<<(BN * 16 + 255) / 256, 256, 0, stream>>>(
        scr_pacc, scr_pl, d2_wo, d2_bo, e2, BN, KSPLIT);
    // pol + val QKV (fused)
    qkv16_dual_kernel<<<(2 * 3 * BN * 16 + 255) / 256, 256, 0, stream>>>(
        e2, pol_wqkv, pol_bqkv, val_wqkv, val_bqkv, qkvp, qkvv, BN);
    // pol + val attention fused (two sets)
    attn_lds_kernel<4, 2><<<dim3(2 * B * H, N / 128, KSPLIT), 256, 0, stream>>>(
        qkvp, qkvp + BN * 16, qkvp + 2 * BN * 16,
        qkvv, qkvv + BN * 16, qkvv + 2 * BN * 16,
        mask, paccp, plp, paccv, plv, B, H, N, qmul2);
    // pol/val combine + head projections (fused)
    heads_fused_kernel<<<(BN + 255) / 256, 256, 0, stream>>>(
        paccp, plp, paccv, plv, pol_wo, pol_bo, val_wo, val_bo, araw, craw, BN, KSPLIT);
    // masked action softmax + critic in one launch
    final_kernel<<<2 * B, 256, 0, stream>>>(
        araw, mask, craw, v2_w, v2_b, out_action, out_critic, N, B);
}